// Round 1
// baseline (660.403 us; speedup 1.0000x reference)
//
#include <hip/hip_runtime.h>

#define NPTS 65536
#define CC 16
#define PH 128
#define SW 256
#define MB 64    // points per subnet block
#define SP 264   // LDS row stride in halves (528 B, 16B-aligned)
#define TS 2.8853900817779268f  // 2*log2(e), folded into weights/biases

typedef _Float16 half8 __attribute__((ext_vector_type(8)));
typedef _Float16 half4 __attribute__((ext_vector_type(4)));
typedef _Float16 half2 __attribute__((ext_vector_type(2)));
typedef float float4_ __attribute__((ext_vector_type(4)));
typedef float float2_ __attribute__((ext_vector_type(2)));
typedef unsigned int uint2_ __attribute__((ext_vector_type(2)));

// tanh with pre-scaled argument: y = 2*log2(e)*x already; tanh = 1 - 2*rcp(exp2(y)+1)
__device__ __forceinline__ float tanh_e(float y) {
    float e = __builtin_amdgcn_exp2f(y);
    float r = __builtin_amdgcn_rcpf(e + 1.0f);
    return fmaf(-2.0f, r, 1.0f);
}

__device__ __forceinline__ void store_pk4(_Float16* p, float a, float b, float c, float d) {
    uint2_ u;
    u.x = __builtin_bit_cast(unsigned int, __builtin_amdgcn_cvt_pkrtz(a, b));
    u.y = __builtin_bit_cast(unsigned int, __builtin_amdgcn_cvt_pkrtz(c, d));
    *(uint2_*)p = u;
}

// ---- kernel 1: transpose+convert sub_Wmid [cl][w][v] f32 -> Wt [cl][v][w] f16
// folds the tanh argument scale TS into the weights (MFMA then emits exp2 arg)
__global__ __launch_bounds__(256) void prep_wt(const float* __restrict__ Wmid,
                                               _Float16* __restrict__ Wt) {
    __shared__ float T[64][65];
    int b = blockIdx.x;      // b = cl*16 + tile
    int cl = b >> 4;
    int tile = b & 15;
    int w0 = (tile >> 2) * 64, v0 = (tile & 3) * 64;
    int t = threadIdx.x;
    int col = t & 63, row4 = t >> 6;
    const float* src = Wmid + ((size_t)cl << 16);
#pragma unroll
    for (int rr = 0; rr < 16; ++rr) {
        int wl = rr * 4 + row4;
        T[wl][col] = src[(size_t)(w0 + wl) * 256 + v0 + col];
    }
    __syncthreads();
    _Float16* dst = Wt + ((size_t)cl << 16);
#pragma unroll
    for (int rr = 0; rr < 16; ++rr) {
        int v = rr * 4 + row4;
        dst[(size_t)(v0 + v) * 256 + w0 + col] = (_Float16)(T[col][v] * TS);
    }
}

// ---- kernel 2: PoU gating net (fp32) -> wgtT[c][n] (transposed for subnet) --
__global__ __launch_bounds__(256) void pou_kernel(
    const float* __restrict__ x, const float* __restrict__ W0,
    const float* __restrict__ b0, const float* __restrict__ Wmid,
    const float* __restrict__ bmid, const float* __restrict__ Wl,
    const float* __restrict__ bl, float* __restrict__ wgtT) {
    __shared__ float hA[64][PH + 1];
    int t = threadIdx.x;
    int p = t & 63;
    int g4 = __builtin_amdgcn_readfirstlane(t >> 6);
    int jb = g4 * 32;
    int n0 = blockIdx.x * 64;
    float x0 = x[(size_t)(n0 + p) * 2];
    float x1 = x[(size_t)(n0 + p) * 2 + 1];

#pragma unroll
    for (int jj = 0; jj < 32; ++jj) {
        int j = jb + jj;
        float a = x0 * W0[j] + x1 * W0[PH + j] + b0[j];
        hA[p][j] = a > 0.f ? a : 0.f;
    }
    __syncthreads();

    for (int l = 0; l < 2; ++l) {
        float acc[32];
#pragma unroll
        for (int jj = 0; jj < 32; ++jj) acc[jj] = bmid[l * PH + jb + jj];
        for (int k = 0; k < PH; ++k) {
            float hv = hA[p][k];
#pragma unroll
            for (int jj = 0; jj < 32; ++jj)
                acc[jj] += hv * Wmid[(l * PH + k) * PH + jb + jj];
        }
        float resv[32];
#pragma unroll
        for (int jj = 0; jj < 32; ++jj) resv[jj] = hA[p][jb + jj];
        __syncthreads();
#pragma unroll
        for (int jj = 0; jj < 32; ++jj) {
            float r = acc[jj] > 0.f ? acc[jj] : 0.f;
            hA[p][jb + jj] = resv[jj] + r;
        }
        __syncthreads();
    }

    int c4 = g4 * 4;
    float lacc[4];
#pragma unroll
    for (int cc = 0; cc < 4; ++cc) lacc[cc] = bl[c4 + cc];
    for (int k = 0; k < PH; ++k) {
        float hv = hA[p][k];
#pragma unroll
        for (int cc = 0; cc < 4; ++cc) lacc[cc] += hv * Wl[k * CC + c4 + cc];
    }
    __syncthreads();
#pragma unroll
    for (int cc = 0; cc < 4; ++cc) hA[p][c4 + cc] = lacc[cc];
    __syncthreads();

    if (t < 64) {
        float lg[CC];
#pragma unroll
        for (int c = 0; c < CC; ++c) lg[c] = hA[t][c];
        float m = lg[0];
#pragma unroll
        for (int c = 1; c < CC; ++c) m = fmaxf(m, lg[c]);
        float s = 0.f;
#pragma unroll
        for (int c = 0; c < CC; ++c) {
            lg[c] = __builtin_amdgcn_exp2f((lg[c] - m) * 1.4426950408889634f);
            s += lg[c];
        }
        float inv = 1.0f / s;
        // transposed store: wgtT[c][n] -> coalesced read in subnet
#pragma unroll
        for (int c = 0; c < CC; ++c)
            wgtT[(size_t)c * NPTS + n0 + t] = lg[c] * inv;
    }
}

// ---- kernel 3: batched subnets (f16 MFMA) -> atomicAdd into out ----
// MB=64: 4 waves; wave w owns neurons [w*64,+64) x all 64 points.
// Weights pre-scaled by TS so MFMA output IS the exp2 argument (saves one
// VALU mul per tanh). L1 tanh runs in-place on acc BEFORE the barrier so
// the block-serialized inter-barrier window is just pack+store.
__global__ __launch_bounds__(256, 4) void subnet_kernel(
    const float* __restrict__ x, const float* __restrict__ centers,
    const float* __restrict__ scales, const float* __restrict__ W0,
    const float* __restrict__ b0, const _Float16* __restrict__ Wt,
    const float* __restrict__ bmid, const float* __restrict__ Wl,
    const float* __restrict__ bl, const float* __restrict__ wgtT,
    float* __restrict__ out) {
    __shared__ _Float16 g[MB * SP];
    __shared__ float part[4][MB];
    int t = threadIdx.x;
    int c = blockIdx.y;
    int n0 = blockIdx.x * MB;

    // layer 0: thread owns 4 consecutive neurons x 16 points; x loads are
    // wave-uniform (L1 broadcast); scales are exact pow2 so rcp-mul is exact
    {
        float cx0 = centers[c * 2], cx1 = centers[c * 2 + 1];
        float is0 = 1.0f / scales[c * 2], is1 = 1.0f / scales[c * 2 + 1];
        int ln = t & 63;          // neuron quad: neurons ln*4..ln*4+3
        int pb = (t >> 6) * 16;   // 16 points
        const float* W0c = W0 + (size_t)c * 2 * SW;
        float4_ w0 = *(const float4_*)&W0c[ln * 4];
        float4_ w1 = *(const float4_*)&W0c[SW + ln * 4];
        float4_ bb = *(const float4_*)&b0[c * SW + ln * 4];
        w0 *= TS; w1 *= TS; bb *= TS;   // fold tanh scale
#pragma unroll 4
        for (int p = 0; p < 16; ++p) {
            float2_ xv = *(const float2_*)&x[(size_t)(n0 + pb + p) * 2];
            float xn0 = (xv[0] - cx0) * is0;
            float xn1 = (xv[1] - cx1) * is1;
            float tv[4];
#pragma unroll
            for (int j = 0; j < 4; ++j)
                tv[j] = tanh_e(fmaf(xn0, w0[j], fmaf(xn1, w1[j], bb[j])));
            store_pk4(&g[(pb + p) * SP + ln * 4], tv[0], tv[1], tv[2], tv[3]);
        }
    }
    __syncthreads();

    int lane = t & 63;
    int wave = t >> 6;
    int quad = lane >> 4;
    int l16 = lane & 15;
    int mb = wave * 64;  // this wave's 64-neuron strip

    // ---- layer 1: MFMA (scaled bias in C) + tanh epilogue back to g ----
    {
        const _Float16* Wp = Wt + (((size_t)(c * 2 + 0)) << 16);
        const _Float16* Arow = Wp + (mb + l16) * SW + quad * 8;
        const float* bp = bmid + (c * 2 + 0) * SW + mb + quad * 4;
        float4_ acc[4][4];
#pragma unroll
        for (int mt = 0; mt < 4; ++mt) {
            float4_ bv = *(const float4_*)&bp[mt * 16];
            bv *= TS;
#pragma unroll
            for (int nt = 0; nt < 4; ++nt) acc[mt][nt] = bv;
        }
        __builtin_amdgcn_s_setprio(1);
#pragma unroll
        for (int kt = 0; kt < 8; ++kt) {
            half8 a[4], b[4];
#pragma unroll
            for (int mt = 0; mt < 4; ++mt)
                a[mt] = *(const half8*)&Arow[mt * 16 * SW + kt * 32];
#pragma unroll
            for (int nt = 0; nt < 4; ++nt)
                b[nt] = *(const half8*)&g[(nt * 16 + l16) * SP + kt * 32 + quad * 8];
#pragma unroll
            for (int mt = 0; mt < 4; ++mt)
#pragma unroll
                for (int nt = 0; nt < 4; ++nt)
                    acc[mt][nt] = __builtin_amdgcn_mfma_f32_16x16x32_f16(
                        a[mt], b[nt], acc[mt][nt], 0, 0, 0);
        }
        __builtin_amdgcn_s_setprio(0);
        // tanh in-place BEFORE the barrier: overlaps other waves' MFMA tail,
        // and shrinks the serialized store window to pack+ds_write only
#pragma unroll
        for (int mt = 0; mt < 4; ++mt)
#pragma unroll
            for (int nt = 0; nt < 4; ++nt) {
                acc[mt][nt][0] = tanh_e(acc[mt][nt][0]);
                acc[mt][nt][1] = tanh_e(acc[mt][nt][1]);
                acc[mt][nt][2] = tanh_e(acc[mt][nt][2]);
                acc[mt][nt][3] = tanh_e(acc[mt][nt][3]);
            }
        __syncthreads();  // all waves done READING g
#pragma unroll
        for (int mt = 0; mt < 4; ++mt) {
#pragma unroll
            for (int nt = 0; nt < 4; ++nt) {
                store_pk4(&g[(nt * 16 + l16) * SP + mb + mt * 16 + quad * 4],
                          acc[mt][nt][0], acc[mt][nt][1],
                          acc[mt][nt][2], acc[mt][nt][3]);
            }
        }
        __syncthreads();
    }

    // ---- layer 2: MFMA (scaled bias in C) + fused tanh*Wl dot ----
    {
        const _Float16* Wp = Wt + (((size_t)(c * 2 + 1)) << 16);
        const _Float16* Arow = Wp + (mb + l16) * SW + quad * 8;
        const float* bp = bmid + (c * 2 + 1) * SW + mb + quad * 4;
        float4_ acc[4][4];
#pragma unroll
        for (int mt = 0; mt < 4; ++mt) {
            float4_ bv = *(const float4_*)&bp[mt * 16];
            bv *= TS;
#pragma unroll
            for (int nt = 0; nt < 4; ++nt) acc[mt][nt] = bv;
        }
        __builtin_amdgcn_s_setprio(1);
#pragma unroll
        for (int kt = 0; kt < 8; ++kt) {
            half8 a[4], b[4];
#pragma unroll
            for (int mt = 0; mt < 4; ++mt)
                a[mt] = *(const half8*)&Arow[mt * 16 * SW + kt * 32];
#pragma unroll
            for (int nt = 0; nt < 4; ++nt)
                b[nt] = *(const half8*)&g[(nt * 16 + l16) * SP + kt * 32 + quad * 8];
#pragma unroll
            for (int mt = 0; mt < 4; ++mt)
#pragma unroll
                for (int nt = 0; nt < 4; ++nt)
                    acc[mt][nt] = __builtin_amdgcn_mfma_f32_16x16x32_f16(
                        a[mt], b[nt], acc[mt][nt], 0, 0, 0);
        }
        __builtin_amdgcn_s_setprio(0);
        const float* wlp = Wl + c * SW + mb + quad * 4;
        float s[4] = {0.f, 0.f, 0.f, 0.f};
#pragma unroll
        for (int mt = 0; mt < 4; ++mt) {
            float4_ wv = *(const float4_*)&wlp[mt * 16];
#pragma unroll
            for (int nt = 0; nt < 4; ++nt) {
                float t0 = tanh_e(acc[mt][nt][0]);
                float t1 = tanh_e(acc[mt][nt][1]);
                float t2 = tanh_e(acc[mt][nt][2]);
                float t3 = tanh_e(acc[mt][nt][3]);
                s[nt] += fmaf(t0, wv[0],
                          fmaf(t1, wv[1], fmaf(t2, wv[2], t3 * wv[3])));
            }
        }
        // reduce over quads (lanes l16, l16+16, l16+32, l16+48)
#pragma unroll
        for (int nt = 0; nt < 4; ++nt) {
            s[nt] += __shfl_xor(s[nt], 16);
            s[nt] += __shfl_xor(s[nt], 32);
        }
        if (quad == 0) {
#pragma unroll
            for (int nt = 0; nt < 4; ++nt) part[wave][nt * 16 + l16] = s[nt];
        }
    }
    __syncthreads();
    if (t < MB) {
        int n = n0 + t;
        float uv = part[0][t] + part[1][t] + part[2][t] + part[3][t] + bl[c];
        float w = wgtT[(size_t)c * NPTS + n];
        float2_ xv = *(const float2_*)&x[(size_t)n * 2];
        float ans = (xv[0] * (1.f - xv[0])) * (xv[1] * (1.f - xv[1]));
        atomicAdd(&out[n], uv * w * ans);
    }
}

extern "C" void kernel_launch(void* const* d_in, const int* in_sizes, int n_in,
                              void* d_out, int out_size, void* d_ws, size_t ws_size,
                              hipStream_t stream) {
    const float* x = (const float*)d_in[0];
    const float* centers = (const float*)d_in[1];
    const float* scales = (const float*)d_in[2];
    const float* pou_W0 = (const float*)d_in[3];
    const float* pou_b0 = (const float*)d_in[4];
    const float* pou_Wmid = (const float*)d_in[5];
    const float* pou_bmid = (const float*)d_in[6];
    const float* pou_Wl = (const float*)d_in[7];
    const float* pou_bl = (const float*)d_in[8];
    const float* sub_W0 = (const float*)d_in[9];
    const float* sub_b0 = (const float*)d_in[10];
    const float* sub_Wmid = (const float*)d_in[11];
    const float* sub_bmid = (const float*)d_in[12];
    const float* sub_Wl = (const float*)d_in[13];
    const float* sub_bl = (const float*)d_in[14];
    float* out = (float*)d_out;

    _Float16* wt = (_Float16*)d_ws;                         // 4 MB
    float* wgtT = (float*)((char*)d_ws + (4u << 20));       // 4 MB

    hipMemsetAsync(out, 0, (size_t)out_size * sizeof(float), stream);
    prep_wt<<<dim3(512), dim3(256), 0, stream>>>(sub_Wmid, wt);
    pou_kernel<<<dim3(NPTS / 64), dim3(256), 0, stream>>>(
        x, pou_W0, pou_b0, pou_Wmid, pou_bmid, pou_Wl, pou_bl, wgtT);
    subnet_kernel<<<dim3(NPTS / MB, CC), dim3(256), 0, stream>>>(
        x, centers, scales, sub_W0, sub_b0, wt, sub_bmid, sub_Wl, sub_bl,
        wgtT, out);
}

// Round 2
// 652.512 us; speedup vs baseline: 1.0121x; 1.0121x over previous
//
#include <hip/hip_runtime.h>

#define NPTS 65536
#define CC 16
#define PH 128
#define SW 256
#define MB 64    // points per subnet block
#define SP 264   // LDS row stride in halves (528 B, 16B-aligned)
#define TS 2.8853900817779268f   // 2*log2(e): exp2 arg scale
#define WS (-5.7707801635558536f) // -2*TS: folds h->tanh affine into next layer

typedef _Float16 half8 __attribute__((ext_vector_type(8)));
typedef _Float16 half4 __attribute__((ext_vector_type(4)));
typedef _Float16 half2 __attribute__((ext_vector_type(2)));
typedef float float4_ __attribute__((ext_vector_type(4)));
typedef float float2_ __attribute__((ext_vector_type(2)));
typedef unsigned int uint2_ __attribute__((ext_vector_type(2)));

// Batched "half-sigmoid": h_i = 1/(exp2(y_i)+1) - 0.5 = -tanh(x_i)/2 for
// y = 2*log2e*x.  One v_rcp for 4 values via product trick; y clamped to 30
// so the 4-term product <= 2^122 (no overflow, correct saturation h->-0.5).
__device__ __forceinline__ float4_ href4(float4_ y) {
    float a0 = __builtin_amdgcn_exp2f(fminf(y[0], 30.f)) + 1.f;
    float a1 = __builtin_amdgcn_exp2f(fminf(y[1], 30.f)) + 1.f;
    float a2 = __builtin_amdgcn_exp2f(fminf(y[2], 30.f)) + 1.f;
    float a3 = __builtin_amdgcn_exp2f(fminf(y[3], 30.f)) + 1.f;
    float q2 = a0 * a1;
    float q3 = q2 * a2;
    float q4 = q3 * a3;
    float r = __builtin_amdgcn_rcpf(q4);   // 1/(a0 a1 a2 a3)
    float4_ h;
    h[3] = fmaf(r, q3, -0.5f);             // 1/a3 - 0.5
    r *= a3;                               // 1/(a0 a1 a2)
    h[2] = fmaf(r, q2, -0.5f);             // 1/a2 - 0.5
    r *= a2;                               // 1/(a0 a1)
    h[1] = fmaf(r, a0, -0.5f);             // 1/a1 - 0.5
    r *= a1;                               // 1/a0
    h[0] = r - 0.5f;
    return h;
}

__device__ __forceinline__ void store_pk4(_Float16* p, float4_ v) {
    uint2_ u;
    u.x = __builtin_bit_cast(unsigned int, __builtin_amdgcn_cvt_pkrtz(v[0], v[1]));
    u.y = __builtin_bit_cast(unsigned int, __builtin_amdgcn_cvt_pkrtz(v[2], v[3]));
    *(uint2_*)p = u;
}

// ---- kernel 1: transpose+convert sub_Wmid [cl][w][v] f32 -> Wt [cl][v][w] f16
// scale by -2*TS: consumes h-stored activations AND pre-scales for next exp2
__global__ __launch_bounds__(256) void prep_wt(const float* __restrict__ Wmid,
                                               _Float16* __restrict__ Wt) {
    __shared__ float T[64][65];
    int b = blockIdx.x;      // b = cl*16 + tile
    int cl = b >> 4;
    int tile = b & 15;
    int w0 = (tile >> 2) * 64, v0 = (tile & 3) * 64;
    int t = threadIdx.x;
    int col = t & 63, row4 = t >> 6;
    const float* src = Wmid + ((size_t)cl << 16);
#pragma unroll
    for (int rr = 0; rr < 16; ++rr) {
        int wl = rr * 4 + row4;
        T[wl][col] = src[(size_t)(w0 + wl) * 256 + v0 + col];
    }
    __syncthreads();
    _Float16* dst = Wt + ((size_t)cl << 16);
#pragma unroll
    for (int rr = 0; rr < 16; ++rr) {
        int v = rr * 4 + row4;
        dst[(size_t)(v0 + v) * 256 + w0 + col] = (_Float16)(T[col][v] * WS);
    }
}

// ---- kernel 2: PoU gating net (fp32) -> wgtT[c][n] (transposed for subnet) --
__global__ __launch_bounds__(256) void pou_kernel(
    const float* __restrict__ x, const float* __restrict__ W0,
    const float* __restrict__ b0, const float* __restrict__ Wmid,
    const float* __restrict__ bmid, const float* __restrict__ Wl,
    const float* __restrict__ bl, float* __restrict__ wgtT) {
    __shared__ float hA[64][PH + 1];
    int t = threadIdx.x;
    int p = t & 63;
    int g4 = __builtin_amdgcn_readfirstlane(t >> 6);
    int jb = g4 * 32;
    int n0 = blockIdx.x * 64;
    float x0 = x[(size_t)(n0 + p) * 2];
    float x1 = x[(size_t)(n0 + p) * 2 + 1];

#pragma unroll
    for (int jj = 0; jj < 32; ++jj) {
        int j = jb + jj;
        float a = x0 * W0[j] + x1 * W0[PH + j] + b0[j];
        hA[p][j] = a > 0.f ? a : 0.f;
    }
    __syncthreads();

    for (int l = 0; l < 2; ++l) {
        float acc[32];
#pragma unroll
        for (int jj = 0; jj < 32; ++jj) acc[jj] = bmid[l * PH + jb + jj];
        for (int k = 0; k < PH; ++k) {
            float hv = hA[p][k];
#pragma unroll
            for (int jj = 0; jj < 32; ++jj)
                acc[jj] += hv * Wmid[(l * PH + k) * PH + jb + jj];
        }
        float resv[32];
#pragma unroll
        for (int jj = 0; jj < 32; ++jj) resv[jj] = hA[p][jb + jj];
        __syncthreads();
#pragma unroll
        for (int jj = 0; jj < 32; ++jj) {
            float r = acc[jj] > 0.f ? acc[jj] : 0.f;
            hA[p][jb + jj] = resv[jj] + r;
        }
        __syncthreads();
    }

    int c4 = g4 * 4;
    float lacc[4];
#pragma unroll
    for (int cc = 0; cc < 4; ++cc) lacc[cc] = bl[c4 + cc];
    for (int k = 0; k < PH; ++k) {
        float hv = hA[p][k];
#pragma unroll
        for (int cc = 0; cc < 4; ++cc) lacc[cc] += hv * Wl[k * CC + c4 + cc];
    }
    __syncthreads();
#pragma unroll
    for (int cc = 0; cc < 4; ++cc) hA[p][c4 + cc] = lacc[cc];
    __syncthreads();

    if (t < 64) {
        float lg[CC];
#pragma unroll
        for (int c = 0; c < CC; ++c) lg[c] = hA[t][c];
        float m = lg[0];
#pragma unroll
        for (int c = 1; c < CC; ++c) m = fmaxf(m, lg[c]);
        float s = 0.f;
#pragma unroll
        for (int c = 0; c < CC; ++c) {
            lg[c] = __builtin_amdgcn_exp2f((lg[c] - m) * 1.4426950408889634f);
            s += lg[c];
        }
        float inv = 1.0f / s;
        // transposed store: wgtT[c][n] -> coalesced read in subnet
#pragma unroll
        for (int c = 0; c < CC; ++c)
            wgtT[(size_t)c * NPTS + n0 + t] = lg[c] * inv;
    }
}

// ---- kernel 3: batched subnets (f16 MFMA) -> atomicAdd into out ----
// MB=64: 4 waves; wave w owns neurons [w*64,+64) x all 64 points.
// Activations stored as h = -tanh/2 (full rel. precision near 0); the -2x
// affine is folded into Wt (WS) and the final output (bl - 2*sum).
// tanh trans-pipe cost cut via batched rcp (href4): 2 trans -> 1.25 / act.
__global__ __launch_bounds__(256, 4) void subnet_kernel(
    const float* __restrict__ x, const float* __restrict__ centers,
    const float* __restrict__ scales, const float* __restrict__ W0,
    const float* __restrict__ b0, const _Float16* __restrict__ Wt,
    const float* __restrict__ bmid, const float* __restrict__ Wl,
    const float* __restrict__ bl, const float* __restrict__ wgtT,
    float* __restrict__ out) {
    __shared__ _Float16 g[MB * SP];
    __shared__ float part[4][MB];
    int t = threadIdx.x;
    int c = blockIdx.y;
    int n0 = blockIdx.x * MB;

    // layer 0: thread owns 4 consecutive neurons x 16 points; x loads are
    // wave-uniform (L1 broadcast); scales are exact pow2 so rcp-mul is exact
    {
        float cx0 = centers[c * 2], cx1 = centers[c * 2 + 1];
        float is0 = 1.0f / scales[c * 2], is1 = 1.0f / scales[c * 2 + 1];
        int ln = t & 63;          // neuron quad: neurons ln*4..ln*4+3
        int pb = (t >> 6) * 16;   // 16 points
        const float* W0c = W0 + (size_t)c * 2 * SW;
        float4_ w0 = *(const float4_*)&W0c[ln * 4];
        float4_ w1 = *(const float4_*)&W0c[SW + ln * 4];
        float4_ bb = *(const float4_*)&b0[c * SW + ln * 4];
        w0 *= TS; w1 *= TS; bb *= TS;   // fold tanh/exp2 scale
#pragma unroll 4
        for (int p = 0; p < 16; ++p) {
            float2_ xv = *(const float2_*)&x[(size_t)(n0 + pb + p) * 2];
            float xn0 = (xv[0] - cx0) * is0;
            float xn1 = (xv[1] - cx1) * is1;
            float4_ y;
#pragma unroll
            for (int j = 0; j < 4; ++j)
                y[j] = fmaf(xn0, w0[j], fmaf(xn1, w1[j], bb[j]));
            store_pk4(&g[(pb + p) * SP + ln * 4], href4(y));
        }
    }
    __syncthreads();

    int lane = t & 63;
    int wave = t >> 6;
    int quad = lane >> 4;
    int l16 = lane & 15;
    int mb = wave * 64;  // this wave's 64-neuron strip

    // ---- layer 1: MFMA (scaled bias in C) + h epilogue back to g ----
    {
        const _Float16* Wp = Wt + (((size_t)(c * 2 + 0)) << 16);
        const _Float16* Arow = Wp + (mb + l16) * SW + quad * 8;
        const float* bp = bmid + (c * 2 + 0) * SW + mb + quad * 4;
        float4_ acc[4][4];
#pragma unroll
        for (int mt = 0; mt < 4; ++mt) {
            float4_ bv = *(const float4_*)&bp[mt * 16];
            bv *= TS;
#pragma unroll
            for (int nt = 0; nt < 4; ++nt) acc[mt][nt] = bv;
        }
#pragma unroll
        for (int kt = 0; kt < 8; ++kt) {
            half8 a[4], b[4];
#pragma unroll
            for (int mt = 0; mt < 4; ++mt)
                a[mt] = *(const half8*)&Arow[mt * 16 * SW + kt * 32];
#pragma unroll
            for (int nt = 0; nt < 4; ++nt)
                b[nt] = *(const half8*)&g[(nt * 16 + l16) * SP + kt * 32 + quad * 8];
#pragma unroll
            for (int mt = 0; mt < 4; ++mt)
#pragma unroll
                for (int nt = 0; nt < 4; ++nt)
                    acc[mt][nt] = __builtin_amdgcn_mfma_f32_16x16x32_f16(
                        a[mt], b[nt], acc[mt][nt], 0, 0, 0);
        }
        // h in-place BEFORE the barrier: overlaps other waves' MFMA tail,
        // and shrinks the serialized store window to pack+ds_write only
#pragma unroll
        for (int mt = 0; mt < 4; ++mt)
#pragma unroll
            for (int nt = 0; nt < 4; ++nt)
                acc[mt][nt] = href4(acc[mt][nt]);
        __syncthreads();  // all waves done READING g
#pragma unroll
        for (int mt = 0; mt < 4; ++mt)
#pragma unroll
            for (int nt = 0; nt < 4; ++nt)
                store_pk4(&g[(nt * 16 + l16) * SP + mb + mt * 16 + quad * 4],
                          acc[mt][nt]);
        __syncthreads();
    }

    // ---- layer 2: MFMA (scaled bias in C) + fused h*Wl dot ----
    {
        const _Float16* Wp = Wt + (((size_t)(c * 2 + 1)) << 16);
        const _Float16* Arow = Wp + (mb + l16) * SW + quad * 8;
        const float* bp = bmid + (c * 2 + 1) * SW + mb + quad * 4;
        float4_ acc[4][4];
#pragma unroll
        for (int mt = 0; mt < 4; ++mt) {
            float4_ bv = *(const float4_*)&bp[mt * 16];
            bv *= TS;
#pragma unroll
            for (int nt = 0; nt < 4; ++nt) acc[mt][nt] = bv;
        }
#pragma unroll
        for (int kt = 0; kt < 8; ++kt) {
            half8 a[4], b[4];
#pragma unroll
            for (int mt = 0; mt < 4; ++mt)
                a[mt] = *(const half8*)&Arow[mt * 16 * SW + kt * 32];
#pragma unroll
            for (int nt = 0; nt < 4; ++nt)
                b[nt] = *(const half8*)&g[(nt * 16 + l16) * SP + kt * 32 + quad * 8];
#pragma unroll
            for (int mt = 0; mt < 4; ++mt)
#pragma unroll
                for (int nt = 0; nt < 4; ++nt)
                    acc[mt][nt] = __builtin_amdgcn_mfma_f32_16x16x32_f16(
                        a[mt], b[nt], acc[mt][nt], 0, 0, 0);
        }
        const float* wlp = Wl + c * SW + mb + quad * 4;
        float s[4] = {0.f, 0.f, 0.f, 0.f};
#pragma unroll
        for (int mt = 0; mt < 4; ++mt) {
            float4_ wv = *(const float4_*)&wlp[mt * 16];
#pragma unroll
            for (int nt = 0; nt < 4; ++nt) {
                float4_ h = href4(acc[mt][nt]);
                s[nt] += fmaf(h[0], wv[0],
                          fmaf(h[1], wv[1], fmaf(h[2], wv[2], h[3] * wv[3])));
            }
        }
        // reduce over quads (lanes l16, l16+16, l16+32, l16+48)
#pragma unroll
        for (int nt = 0; nt < 4; ++nt) {
            s[nt] += __shfl_xor(s[nt], 16);
            s[nt] += __shfl_xor(s[nt], 32);
        }
        if (quad == 0) {
#pragma unroll
            for (int nt = 0; nt < 4; ++nt) part[wave][nt * 16 + l16] = s[nt];
        }
    }
    __syncthreads();
    if (t < MB) {
        int n = n0 + t;
        // u = bl + sum(wl*tanh) = bl - 2*sum(wl*h)
        float uv = fmaf(-2.f, part[0][t] + part[1][t] + part[2][t] + part[3][t],
                        bl[c]);
        float w = wgtT[(size_t)c * NPTS + n];
        float2_ xv = *(const float2_*)&x[(size_t)n * 2];
        float ans = (xv[0] * (1.f - xv[0])) * (xv[1] * (1.f - xv[1]));
        atomicAdd(&out[n], uv * w * ans);
    }
}

extern "C" void kernel_launch(void* const* d_in, const int* in_sizes, int n_in,
                              void* d_out, int out_size, void* d_ws, size_t ws_size,
                              hipStream_t stream) {
    const float* x = (const float*)d_in[0];
    const float* centers = (const float*)d_in[1];
    const float* scales = (const float*)d_in[2];
    const float* pou_W0 = (const float*)d_in[3];
    const float* pou_b0 = (const float*)d_in[4];
    const float* pou_Wmid = (const float*)d_in[5];
    const float* pou_bmid = (const float*)d_in[6];
    const float* pou_Wl = (const float*)d_in[7];
    const float* pou_bl = (const float*)d_in[8];
    const float* sub_W0 = (const float*)d_in[9];
    const float* sub_b0 = (const float*)d_in[10];
    const float* sub_Wmid = (const float*)d_in[11];
    const float* sub_bmid = (const float*)d_in[12];
    const float* sub_Wl = (const float*)d_in[13];
    const float* sub_bl = (const float*)d_in[14];
    float* out = (float*)d_out;

    _Float16* wt = (_Float16*)d_ws;                         // 4 MB
    float* wgtT = (float*)((char*)d_ws + (4u << 20));       // 4 MB

    hipMemsetAsync(out, 0, (size_t)out_size * sizeof(float), stream);
    prep_wt<<<dim3(512), dim3(256), 0, stream>>>(sub_Wmid, wt);
    pou_kernel<<<dim3(NPTS / 64), dim3(256), 0, stream>>>(
        x, pou_W0, pou_b0, pou_Wmid, pou_bmid, pou_Wl, pou_bl, wgtT);
    subnet_kernel<<<dim3(NPTS / MB, CC), dim3(256), 0, stream>>>(
        x, centers, scales, sub_W0, sub_b0, wt, sub_bmid, sub_Wl, sub_bl,
        wgtT, out);
}